// Round 8
// baseline (309.751 us; speedup 1.0000x reference)
//
#include <hip/hip_runtime.h>

// GCN: 2x (GCNConv + ReLU) + FC.  N=100000, E=1600000, F: 128 -> 64 -> 64 -> 32. fp32.
//
// R8: two fixes from R7 rocprof.
// (1) mm1 K=128 Xs swizzle key was wrong (r&3 — identical for the 4 conflicting
//     rows {i,i+4,i+8,i+12}; 3.2M SQ_LDS_BANK_CONFLICT remained). Now (r>>2)&3.
// (2) agg was instruction-bound (VALUBusy 68%, 2 vmem/edge): lanes now own a
//     feature PAIR (ushort2 dword); half-waves take even/odd edges, so one
//     gather instruction covers 2 edges; unpredicated 8-edge main chunks +
//     single predicated tail chunk. Halves combine via __shfl_xor(32).
// Hs tables bf16 (R7), partition passes unchanged (R6).

#define THREADS 256
#define EPB 4096          // edges per block in hist/bin passes
#define BKT 256           // nodes per bucket (dlocal = dst & 255)
#define SORT_CAP 8192     // max edges per bucket in LDS (mean 4092, sigma ~64)

typedef unsigned short ushort_t;

__device__ __forceinline__ ushort_t f2bf(float f) {  // round-to-nearest-even
    unsigned u = __float_as_uint(f);
    u += 0x7FFFu + ((u >> 16) & 1u);
    return (ushort_t)(u >> 16);
}
__device__ __forceinline__ float bflo(unsigned v) { return __uint_as_float(v << 16); }
__device__ __forceinline__ float bfhi(unsigned v) { return __uint_as_float(v & 0xFFFF0000u); }

// ---- Pass 1: per-(block,bucket) histogram ---------------------------------

__global__ __launch_bounds__(THREADS) void histB_kernel(const int* __restrict__ dst, int E,
                                                        int nb, int nblk,
                                                        int* __restrict__ bh) {
    __shared__ int h[512];
    for (int i = threadIdx.x; i < nb; i += THREADS) h[i] = 0;
    __syncthreads();
    const int e0 = blockIdx.x * EPB;
    const int e1 = min(e0 + EPB, E);
    for (int e = e0 + threadIdx.x; e < e1; e += THREADS)
        atomicAdd(&h[dst[e] >> 8], 1);
    __syncthreads();
    for (int i = threadIdx.x; i < nb; i += THREADS)
        bh[(size_t)i * nblk + blockIdx.x] = h[i];   // [bucket][block]
}

// ---- Pass 2a: per-bucket row scan (block b owns row b) --------------------

__global__ __launch_bounds__(THREADS) void scanS_kernel(int* __restrict__ bh,
                                                        int nb, int nblk,
                                                        int* __restrict__ btot) {
    __shared__ int s[THREADS];
    const int b = blockIdx.x, t = threadIdx.x;
    int* rowp = bh + (size_t)b * nblk;
    const int run = (nblk + THREADS - 1) / THREADS;
    const int lo = min(t * run, nblk), hi = min(lo + run, nblk);
    int v[4];
    int sum = 0;
    for (int i = lo; i < hi; ++i) { v[i - lo] = rowp[i]; sum += v[i - lo]; }
    s[t] = sum;
    __syncthreads();
    for (int off = 1; off < THREADS; off <<= 1) {
        int u = (t >= off) ? s[t - off] : 0;
        __syncthreads();
        s[t] += u;
        __syncthreads();
    }
    int pre = s[t] - sum;
    for (int i = lo; i < hi; ++i) { rowp[i] = pre; pre += v[i - lo]; }
    if (t == THREADS - 1) btot[b] = s[t];
}

// ---- Pass 2b: scan bucket totals -> bstart[0..nb], bstart[nb]=E -----------

__global__ __launch_bounds__(512) void scanT_kernel(const int* __restrict__ btot,
                                                    int nb, int E,
                                                    int* __restrict__ bstart) {
    __shared__ int s[512];
    const int t = threadIdx.x;
    const int v = (t < nb) ? btot[t] : 0;
    s[t] = v;
    __syncthreads();
    for (int off = 1; off < 512; off <<= 1) {
        int u = (t >= off) ? s[t - off] : 0;
        __syncthreads();
        s[t] += u;
        __syncthreads();
    }
    if (t < nb) bstart[t] = s[t] - v;
    if (t == 0) bstart[nb] = E;
}

// ---- Pass 3: scatter edges into bucket-contiguous staging -----------------

__global__ __launch_bounds__(THREADS) void binB_kernel(const int* __restrict__ src,
                                                       const int* __restrict__ dst, int E,
                                                       int nb, int nblk,
                                                       const int* __restrict__ bh,
                                                       const int* __restrict__ bstart,
                                                       unsigned* __restrict__ stage) {
    __shared__ int cur[512];
    for (int i = threadIdx.x; i < nb; i += THREADS)
        cur[i] = bstart[i] + bh[(size_t)i * nblk + blockIdx.x];
    __syncthreads();
    const int e0 = blockIdx.x * EPB;
    const int e1 = min(e0 + EPB, E);
    for (int e = e0 + threadIdx.x; e < e1; e += THREADS) {
        const int d = dst[e];
        const int pos = atomicAdd(&cur[d >> 8], 1);
        stage[pos] = ((unsigned)(d & (BKT - 1)) << 17) | (unsigned)src[e];
    }
}

// ---- Pass 4: per-bucket in-LDS counting sort (in place) + row/dinv --------

__global__ __launch_bounds__(THREADS) void sortB_kernel(unsigned* __restrict__ stage,
                                                        const int* __restrict__ bstart,
                                                        int nb, int N,
                                                        int* __restrict__ row,
                                                        float* __restrict__ dinv) {
    __shared__ unsigned buf[SORT_CAP];
    __shared__ int cnt[BKT], cur[BKT], scn[BKT];
    const int b = blockIdx.x, t = threadIdx.x;
    const int bs = bstart[b];
    const int be = bstart[b + 1];
    const int m = be - bs;
    cnt[t] = 0;
    __syncthreads();
    for (int i = t; i < m; i += THREADS) {
        const unsigned v = stage[bs + i];
        buf[i] = v;
        atomicAdd(&cnt[v >> 17], 1);
    }
    __syncthreads();
    const int c = cnt[t];
    scn[t] = c;
    __syncthreads();
    for (int off = 1; off < BKT; off <<= 1) {
        int u = (t >= off) ? scn[t - off] : 0;
        __syncthreads();
        scn[t] += u;
        __syncthreads();
    }
    const int excl = scn[t] - c;
    cur[t] = excl;
    const int node = b * BKT + t;
    if (node < N) {
        row[node] = bs + excl;
        dinv[node] = rsqrtf((float)c + 1.0f);  // +1 self-loop
    }
    __syncthreads();
    for (int i = t; i < m; i += THREADS) {
        const unsigned v = buf[i];
        const int pos = atomicAdd(&cur[v >> 17], 1);
        stage[bs + pos] = v & 0x1FFFFu;        // strip dlocal: plain src
    }
}

// ---- Dense matmul: Y[N,M] = (X[N,K] @ W[K,M]) [*dinv[row]] [+bias] ---------
// K=128: XOR-rotate Xs columns by ((r>>2)&3)*4 floats — the 4 rows read by one
// wave instr are {i,i+4,i+8,i+12}, distinct (r>>2)&3 -> distinct bank quads.
// K=64: stride pad +4 floats (2-way alias, free).

template <int K, int M, int TILE_R, bool BIAS, bool SCALE, bool OUT_BF16, typename OutT>
__global__ __launch_bounds__(THREADS) void mm_kernel(const float* __restrict__ X,
                                                     const float* __restrict__ W,
                                                     const float* __restrict__ bias,
                                                     const float* __restrict__ dinv,
                                                     OutT* __restrict__ Y, int N) {
    static_assert((TILE_R / 4) * (M / 4) == THREADS, "tile/thread mismatch");
    constexpr bool SWZ = (K == 128);
    constexpr int KP = SWZ ? K : K + 4;
    constexpr int KQ = K / 4;
    __shared__ float Xs[TILE_R * KP];
    __shared__ float Ws[K * M];
    const int t = threadIdx.x;
    const int row0 = blockIdx.x * TILE_R;

    auto xaddr = [](int r, int c) -> int {
        return SWZ ? r * KP + ((c + (((r >> 2) & 3) << 2)) & (K - 1)) : r * KP + c;
    };

    for (int i = t; i < K * M / 4; i += THREADS)
        ((float4*)Ws)[i] = ((const float4*)W)[i];

    const bool full = (row0 + TILE_R <= N);
    for (int i = t; i < TILE_R * KQ; i += THREADS) {
        const int r = i / KQ, kq = i % KQ;
        float4 v = {0.f, 0.f, 0.f, 0.f};
        if (full || row0 + r < N)
            v = *(const float4*)(X + (size_t)(row0 + r) * K + kq * 4);
        *(float4*)&Xs[xaddr(r, kq * 4)] = v;
    }
    __syncthreads();

    constexpr int CG = M / 4;
    const int rg = t / CG;
    const int cg = t % CG;
    float acc[4][4] = {};
    const float* wb = &Ws[cg * 4];

#define GCN_STEP(XV, WV)                                                                  \
    acc[0][0] = fmaf(xv0.XV, WV.x, acc[0][0]); acc[0][1] = fmaf(xv0.XV, WV.y, acc[0][1]); \
    acc[0][2] = fmaf(xv0.XV, WV.z, acc[0][2]); acc[0][3] = fmaf(xv0.XV, WV.w, acc[0][3]); \
    acc[1][0] = fmaf(xv1.XV, WV.x, acc[1][0]); acc[1][1] = fmaf(xv1.XV, WV.y, acc[1][1]); \
    acc[1][2] = fmaf(xv1.XV, WV.z, acc[1][2]); acc[1][3] = fmaf(xv1.XV, WV.w, acc[1][3]); \
    acc[2][0] = fmaf(xv2.XV, WV.x, acc[2][0]); acc[2][1] = fmaf(xv2.XV, WV.y, acc[2][1]); \
    acc[2][2] = fmaf(xv2.XV, WV.z, acc[2][2]); acc[2][3] = fmaf(xv2.XV, WV.w, acc[2][3]); \
    acc[3][0] = fmaf(xv3.XV, WV.x, acc[3][0]); acc[3][1] = fmaf(xv3.XV, WV.y, acc[3][1]); \
    acc[3][2] = fmaf(xv3.XV, WV.z, acc[3][2]); acc[3][3] = fmaf(xv3.XV, WV.w, acc[3][3]);

    for (int k = 0; k < K; k += 4) {
        const float4 xv0 = *(const float4*)&Xs[xaddr(rg * 4 + 0, k)];
        const float4 xv1 = *(const float4*)&Xs[xaddr(rg * 4 + 1, k)];
        const float4 xv2 = *(const float4*)&Xs[xaddr(rg * 4 + 2, k)];
        const float4 xv3 = *(const float4*)&Xs[xaddr(rg * 4 + 3, k)];
        const float4 wv0 = *(const float4*)(wb + (size_t)(k + 0) * M);
        const float4 wv1 = *(const float4*)(wb + (size_t)(k + 1) * M);
        const float4 wv2 = *(const float4*)(wb + (size_t)(k + 2) * M);
        const float4 wv3 = *(const float4*)(wb + (size_t)(k + 3) * M);
        GCN_STEP(x, wv0)
        GCN_STEP(y, wv1)
        GCN_STEP(z, wv2)
        GCN_STEP(w, wv3)
    }
#undef GCN_STEP

#pragma unroll
    for (int i = 0; i < 4; ++i) {
        const int r = row0 + rg * 4 + i;
        if (r < N) {
            float4 o = {acc[i][0], acc[i][1], acc[i][2], acc[i][3]};
            if (SCALE) {
                const float d = dinv[r];
                o.x *= d; o.y *= d; o.z *= d; o.w *= d;
            }
            if (BIAS) {
                o.x += bias[cg * 4 + 0]; o.y += bias[cg * 4 + 1];
                o.z += bias[cg * 4 + 2]; o.w += bias[cg * 4 + 3];
            }
            if (OUT_BF16) {
                ushort4 p = {f2bf(o.x), f2bf(o.y), f2bf(o.z), f2bf(o.w)};
                *(ushort4*)((ushort_t*)Y + (size_t)r * M + cg * 4) = p;
            } else {
                *(float4*)((float*)Y + (size_t)r * M + cg * 4) = o;
            }
        }
    }
}

// ---- Aggregation: wave per node; lane owns a feature PAIR (ushort2 dword);
// half-waves take even/odd edges -> one gather instr covers 2 edges.
// out[i,f] = relu(dinv[i] * (Hs[i,f] + sum_{s in N(i)} Hs[s,f]) + b[f])

__global__ __launch_bounds__(THREADS) void agg_kernel(const unsigned* __restrict__ srt,
                                                      const int* __restrict__ row,
                                                      const float* __restrict__ dinv,
                                                      const unsigned* __restrict__ H2,  // [N][32] dwords (bf16 pairs)
                                                      const float* __restrict__ bias,
                                                      float* __restrict__ out, int N, int E) {
    const int idx = blockIdx.x * blockDim.x + threadIdx.x;
    const int node = idx >> 6;
    if (node >= N) return;
    const int l = threadIdx.x & 63;
    const int half = l >> 5;          // 0: even edges, 1: odd edges
    const int f2 = l & 31;            // feature pair (2*f2, 2*f2+1)
    const int start = row[node];
    const int end = (node + 1 < N) ? row[node + 1] : E;
    float acc0 = 0.0f, acc1 = 0.0f;

    int base = start;
    // Main: full 8-edge chunks, unpredicated (this half-lane takes 4 of them).
    for (; base + 8 <= end; base += 8) {
        const int j = base + half;
        const unsigned sA = srt[j + 0];
        const unsigned sB = srt[j + 2];
        const unsigned sC = srt[j + 4];
        const unsigned sD = srt[j + 6];
        const unsigned vA = H2[(size_t)sA * 32 + f2];
        const unsigned vB = H2[(size_t)sB * 32 + f2];
        const unsigned vC = H2[(size_t)sC * 32 + f2];
        const unsigned vD = H2[(size_t)sD * 32 + f2];
        acc0 += bflo(vA); acc1 += bfhi(vA);
        acc0 += bflo(vB); acc1 += bfhi(vB);
        acc0 += bflo(vC); acc1 += bfhi(vC);
        acc0 += bflo(vD); acc1 += bfhi(vD);
    }
    // Tail: one predicated chunk (up to 7 edges).
    if (base < end) {
        unsigned s[4];
        bool ok[4];
#pragma unroll
        for (int k = 0; k < 4; ++k) {
            const int jj = base + 2 * k + half;
            ok[k] = jj < end;
            s[k] = srt[ok[k] ? jj : start];
        }
        unsigned v[4];
#pragma unroll
        for (int k = 0; k < 4; ++k) v[k] = H2[(size_t)s[k] * 32 + f2];
#pragma unroll
        for (int k = 0; k < 4; ++k) {
            acc0 += ok[k] ? bflo(v[k]) : 0.0f;
            acc1 += ok[k] ? bfhi(v[k]) : 0.0f;
        }
    }

    // Combine even/odd halves; then lanes 0-31 finalize features (2f2, 2f2+1).
    acc0 += __shfl_xor(acc0, 32, 64);
    acc1 += __shfl_xor(acc1, 32, 64);
    if (half == 0) {
        const unsigned sv = H2[(size_t)node * 32 + f2];   // self-loop row
        const float d = dinv[node];
        const float2 b = *(const float2*)(bias + f2 * 2);
        const float o0 = fmaxf(fmaf(acc0 + bflo(sv), d, b.x), 0.0f);
        const float o1 = fmaxf(fmaf(acc1 + bfhi(sv), d, b.y), 0.0f);
        float2 o = {o0, o1};
        *(float2*)(out + (size_t)node * 64 + f2 * 2) = o;
    }
}

// ---- Launch ----------------------------------------------------------------

extern "C" void kernel_launch(void* const* d_in, const int* in_sizes, int n_in,
                              void* d_out, int out_size, void* d_ws, size_t ws_size,
                              hipStream_t stream) {
    const float* x   = (const float*)d_in[0];
    const int*   ei  = (const int*)d_in[1];   // [2, E] int32
    const float* W1  = (const float*)d_in[3];
    const float* b1  = (const float*)d_in[4];
    const float* W2  = (const float*)d_in[5];
    const float* b2  = (const float*)d_in[6];
    const float* Wfc = (const float*)d_in[7];
    const float* bfc = (const float*)d_in[8];
    float* out = (float*)d_out;

    const int N = in_sizes[0] / 128;
    const int E = in_sizes[1] / 2;
    const int* src = ei;
    const int* dst = ei + E;

    const int nb   = (N + BKT - 1) / BKT;     // 391 buckets
    const int nblk = (E + EPB - 1) / EPB;     // 391 edge-chunks

    // ws: bh[nb*nblk] | btot[nb] | bstart[nb+1] | stage[E] | row[N] | dinv[N]
    //     | bufF[N*64] fp32 | bufH[N*64] bf16   (~46 MB)
    int*      bh     = (int*)d_ws;
    int*      btot   = bh + (size_t)nb * nblk;
    int*      bstart = btot + nb;
    unsigned* stage  = (unsigned*)(bstart + nb + 1);
    int*      row    = (int*)(stage + E);
    float*    dinv   = (float*)(row + N);
    float*    bufF   = dinv + N;                             // fp32 [N,64]
    ushort_t* bufH   = (ushort_t*)(bufF + (size_t)N * 64);   // bf16 [N,64]

    const int gW = ((N * 64) + THREADS - 1) / THREADS;  // one wave per node

    // Partition -> sorted CSR (shared by both conv layers).
    histB_kernel<<<nblk, THREADS, 0, stream>>>(dst, E, nb, nblk, bh);
    scanS_kernel<<<nb, THREADS, 0, stream>>>(bh, nb, nblk, btot);
    scanT_kernel<<<1, 512, 0, stream>>>(btot, nb, E, bstart);
    binB_kernel<<<nblk, THREADS, 0, stream>>>(src, dst, E, nb, nblk, bh, bstart, stage);
    sortB_kernel<<<nb, THREADS, 0, stream>>>(stage, bstart, nb, N, row, dinv);

    // Layer 1: Hs1 = bf16((x @ W1)*dinv); relu1 = relu(dinv*(Hs1 self+gather)+b1) fp32
    mm_kernel<128, 64, 64, false, true, true><<<(N + 63) / 64, THREADS, 0, stream>>>(
        x, W1, nullptr, dinv, bufH, N);
    agg_kernel<<<gW, THREADS, 0, stream>>>(stage, row, dinv, (const unsigned*)bufH, b1, bufF, N, E);

    // Layer 2
    mm_kernel<64, 64, 64, false, true, true><<<(N + 63) / 64, THREADS, 0, stream>>>(
        bufF, W2, nullptr, dinv, bufH, N);
    agg_kernel<<<gW, THREADS, 0, stream>>>(stage, row, dinv, (const unsigned*)bufH, b2, bufF, N, E);

    // FC: out = relu2 @ Wfc + bfc (fp32 in/out)
    mm_kernel<64, 32, 128, true, false, false><<<(N + 127) / 128, THREADS, 0, stream>>>(
        bufF, Wfc, bfc, nullptr, out, N);
}

// Round 9
// 300.739 us; speedup vs baseline: 1.0300x; 1.0300x over previous
//
#include <hip/hip_runtime.h>

// GCN: 2x (GCNConv + ReLU) + FC.  N=100000, E=1600000, F: 128 -> 64 -> 64 -> 32. fp32.
//
// R9: mm was occupancy/latency-bound (64 KB LDS -> 2 blocks/CU, 17% occ, VALU 34%).
// X had no cross-thread reuse except the 16 same-rg lanes reading IDENTICAL
// addresses (hw broadcast from one L1 transaction) -> Xs LDS staging removed.
// X streams global->reg with a depth-1 prefetch pipeline; only Ws in LDS
// (32/16/8 KB -> 4-5 blocks/CU), one barrier total, no staging phase.
// agg: pair-gather (R8), Hs bf16 (R7), partition passes (R6) unchanged.

#define THREADS 256
#define EPB 4096          // edges per block in hist/bin passes
#define BKT 256           // nodes per bucket (dlocal = dst & 255)
#define SORT_CAP 8192     // max edges per bucket in LDS (mean 4092, sigma ~64)

typedef unsigned short ushort_t;

__device__ __forceinline__ ushort_t f2bf(float f) {  // round-to-nearest-even
    unsigned u = __float_as_uint(f);
    u += 0x7FFFu + ((u >> 16) & 1u);
    return (ushort_t)(u >> 16);
}
__device__ __forceinline__ float bflo(unsigned v) { return __uint_as_float(v << 16); }
__device__ __forceinline__ float bfhi(unsigned v) { return __uint_as_float(v & 0xFFFF0000u); }

// ---- Pass 1: per-(block,bucket) histogram ---------------------------------

__global__ __launch_bounds__(THREADS) void histB_kernel(const int* __restrict__ dst, int E,
                                                        int nb, int nblk,
                                                        int* __restrict__ bh) {
    __shared__ int h[512];
    for (int i = threadIdx.x; i < nb; i += THREADS) h[i] = 0;
    __syncthreads();
    const int e0 = blockIdx.x * EPB;
    const int e1 = min(e0 + EPB, E);
    for (int e = e0 + threadIdx.x; e < e1; e += THREADS)
        atomicAdd(&h[dst[e] >> 8], 1);
    __syncthreads();
    for (int i = threadIdx.x; i < nb; i += THREADS)
        bh[(size_t)i * nblk + blockIdx.x] = h[i];   // [bucket][block]
}

// ---- Pass 2a: per-bucket row scan (block b owns row b) --------------------

__global__ __launch_bounds__(THREADS) void scanS_kernel(int* __restrict__ bh,
                                                        int nb, int nblk,
                                                        int* __restrict__ btot) {
    __shared__ int s[THREADS];
    const int b = blockIdx.x, t = threadIdx.x;
    int* rowp = bh + (size_t)b * nblk;
    const int run = (nblk + THREADS - 1) / THREADS;
    const int lo = min(t * run, nblk), hi = min(lo + run, nblk);
    int v[4];
    int sum = 0;
    for (int i = lo; i < hi; ++i) { v[i - lo] = rowp[i]; sum += v[i - lo]; }
    s[t] = sum;
    __syncthreads();
    for (int off = 1; off < THREADS; off <<= 1) {
        int u = (t >= off) ? s[t - off] : 0;
        __syncthreads();
        s[t] += u;
        __syncthreads();
    }
    int pre = s[t] - sum;
    for (int i = lo; i < hi; ++i) { rowp[i] = pre; pre += v[i - lo]; }
    if (t == THREADS - 1) btot[b] = s[t];
}

// ---- Pass 2b: scan bucket totals -> bstart[0..nb], bstart[nb]=E -----------

__global__ __launch_bounds__(512) void scanT_kernel(const int* __restrict__ btot,
                                                    int nb, int E,
                                                    int* __restrict__ bstart) {
    __shared__ int s[512];
    const int t = threadIdx.x;
    const int v = (t < nb) ? btot[t] : 0;
    s[t] = v;
    __syncthreads();
    for (int off = 1; off < 512; off <<= 1) {
        int u = (t >= off) ? s[t - off] : 0;
        __syncthreads();
        s[t] += u;
        __syncthreads();
    }
    if (t < nb) bstart[t] = s[t] - v;
    if (t == 0) bstart[nb] = E;
}

// ---- Pass 3: scatter edges into bucket-contiguous staging -----------------

__global__ __launch_bounds__(THREADS) void binB_kernel(const int* __restrict__ src,
                                                       const int* __restrict__ dst, int E,
                                                       int nb, int nblk,
                                                       const int* __restrict__ bh,
                                                       const int* __restrict__ bstart,
                                                       unsigned* __restrict__ stage) {
    __shared__ int cur[512];
    for (int i = threadIdx.x; i < nb; i += THREADS)
        cur[i] = bstart[i] + bh[(size_t)i * nblk + blockIdx.x];
    __syncthreads();
    const int e0 = blockIdx.x * EPB;
    const int e1 = min(e0 + EPB, E);
    for (int e = e0 + threadIdx.x; e < e1; e += THREADS) {
        const int d = dst[e];
        const int pos = atomicAdd(&cur[d >> 8], 1);
        stage[pos] = ((unsigned)(d & (BKT - 1)) << 17) | (unsigned)src[e];
    }
}

// ---- Pass 4: per-bucket in-LDS counting sort (in place) + row/dinv --------

__global__ __launch_bounds__(THREADS) void sortB_kernel(unsigned* __restrict__ stage,
                                                        const int* __restrict__ bstart,
                                                        int nb, int N,
                                                        int* __restrict__ row,
                                                        float* __restrict__ dinv) {
    __shared__ unsigned buf[SORT_CAP];
    __shared__ int cnt[BKT], cur[BKT], scn[BKT];
    const int b = blockIdx.x, t = threadIdx.x;
    const int bs = bstart[b];
    const int be = bstart[b + 1];
    const int m = be - bs;
    cnt[t] = 0;
    __syncthreads();
    for (int i = t; i < m; i += THREADS) {
        const unsigned v = stage[bs + i];
        buf[i] = v;
        atomicAdd(&cnt[v >> 17], 1);
    }
    __syncthreads();
    const int c = cnt[t];
    scn[t] = c;
    __syncthreads();
    for (int off = 1; off < BKT; off <<= 1) {
        int u = (t >= off) ? scn[t - off] : 0;
        __syncthreads();
        scn[t] += u;
        __syncthreads();
    }
    const int excl = scn[t] - c;
    cur[t] = excl;
    const int node = b * BKT + t;
    if (node < N) {
        row[node] = bs + excl;
        dinv[node] = rsqrtf((float)c + 1.0f);  // +1 self-loop
    }
    __syncthreads();
    for (int i = t; i < m; i += THREADS) {
        const unsigned v = buf[i];
        const int pos = atomicAdd(&cur[v >> 17], 1);
        stage[bs + pos] = v & 0x1FFFFu;        // strip dlocal: plain src
    }
}

// ---- Dense matmul: Y[N,M] = (X[N,K] @ W[K,M]) [*dinv[row]] [+bias] ---------
// W-only LDS; X streamed global->reg (16 same-rg lanes share one broadcast
// address). Depth-1 prefetch pipeline; no barrier in the K-loop.
// OOB rows: pointer clamped to N-1; garbage acc discarded by the store guard.

template <int K, int M, int TILE_R, bool BIAS, bool SCALE, bool OUT_BF16, typename OutT>
__global__ __launch_bounds__(THREADS) void mm_kernel(const float* __restrict__ X,
                                                     const float* __restrict__ W,
                                                     const float* __restrict__ bias,
                                                     const float* __restrict__ dinv,
                                                     OutT* __restrict__ Y, int N) {
    static_assert((TILE_R / 4) * (M / 4) == THREADS, "tile/thread mismatch");
    __shared__ float Ws[K * M];
    const int t = threadIdx.x;
    const int row0 = blockIdx.x * TILE_R;

    for (int i = t; i < K * M / 4; i += THREADS)
        ((float4*)Ws)[i] = ((const float4*)W)[i];
    __syncthreads();

    constexpr int CG = M / 4;
    const int rg = t / CG;
    const int cg = t % CG;
    const int r0 = row0 + rg * 4;
    const float* xp0 = X + (size_t)min(r0 + 0, N - 1) * K;
    const float* xp1 = X + (size_t)min(r0 + 1, N - 1) * K;
    const float* xp2 = X + (size_t)min(r0 + 2, N - 1) * K;
    const float* xp3 = X + (size_t)min(r0 + 3, N - 1) * K;
    const float* wb = &Ws[cg * 4];
    float acc[4][4] = {};

#define GCN_STEP(XV, WV)                                                                  \
    acc[0][0] = fmaf(xv0.XV, WV.x, acc[0][0]); acc[0][1] = fmaf(xv0.XV, WV.y, acc[0][1]); \
    acc[0][2] = fmaf(xv0.XV, WV.z, acc[0][2]); acc[0][3] = fmaf(xv0.XV, WV.w, acc[0][3]); \
    acc[1][0] = fmaf(xv1.XV, WV.x, acc[1][0]); acc[1][1] = fmaf(xv1.XV, WV.y, acc[1][1]); \
    acc[1][2] = fmaf(xv1.XV, WV.z, acc[1][2]); acc[1][3] = fmaf(xv1.XV, WV.w, acc[1][3]); \
    acc[2][0] = fmaf(xv2.XV, WV.x, acc[2][0]); acc[2][1] = fmaf(xv2.XV, WV.y, acc[2][1]); \
    acc[2][2] = fmaf(xv2.XV, WV.z, acc[2][2]); acc[2][3] = fmaf(xv2.XV, WV.w, acc[2][3]); \
    acc[3][0] = fmaf(xv3.XV, WV.x, acc[3][0]); acc[3][1] = fmaf(xv3.XV, WV.y, acc[3][1]); \
    acc[3][2] = fmaf(xv3.XV, WV.z, acc[3][2]); acc[3][3] = fmaf(xv3.XV, WV.w, acc[3][3]);

#define GCN_CHUNK(KK)                                                \
    {                                                                \
        const float4 wv0 = *(const float4*)(wb + (size_t)(KK + 0) * M); \
        const float4 wv1 = *(const float4*)(wb + (size_t)(KK + 1) * M); \
        const float4 wv2 = *(const float4*)(wb + (size_t)(KK + 2) * M); \
        const float4 wv3 = *(const float4*)(wb + (size_t)(KK + 3) * M); \
        GCN_STEP(x, wv0)                                             \
        GCN_STEP(y, wv1)                                             \
        GCN_STEP(z, wv2)                                             \
        GCN_STEP(w, wv3)                                             \
    }

    float4 nx0 = *(const float4*)(xp0);
    float4 nx1 = *(const float4*)(xp1);
    float4 nx2 = *(const float4*)(xp2);
    float4 nx3 = *(const float4*)(xp3);
#pragma unroll 4
    for (int k = 0; k < K - 4; k += 4) {
        const float4 xv0 = nx0, xv1 = nx1, xv2 = nx2, xv3 = nx3;
        nx0 = *(const float4*)(xp0 + k + 4);
        nx1 = *(const float4*)(xp1 + k + 4);
        nx2 = *(const float4*)(xp2 + k + 4);
        nx3 = *(const float4*)(xp3 + k + 4);
        GCN_CHUNK(k)
    }
    {
        const float4 xv0 = nx0, xv1 = nx1, xv2 = nx2, xv3 = nx3;
        GCN_CHUNK(K - 4)
    }
#undef GCN_CHUNK
#undef GCN_STEP

#pragma unroll
    for (int i = 0; i < 4; ++i) {
        const int r = r0 + i;
        if (r < N) {
            float4 o = {acc[i][0], acc[i][1], acc[i][2], acc[i][3]};
            if (SCALE) {
                const float d = dinv[r];
                o.x *= d; o.y *= d; o.z *= d; o.w *= d;
            }
            if (BIAS) {
                o.x += bias[cg * 4 + 0]; o.y += bias[cg * 4 + 1];
                o.z += bias[cg * 4 + 2]; o.w += bias[cg * 4 + 3];
            }
            if (OUT_BF16) {
                ushort4 p = {f2bf(o.x), f2bf(o.y), f2bf(o.z), f2bf(o.w)};
                *(ushort4*)((ushort_t*)Y + (size_t)r * M + cg * 4) = p;
            } else {
                *(float4*)((float*)Y + (size_t)r * M + cg * 4) = o;
            }
        }
    }
}

// ---- Aggregation: wave per node; lane owns a feature PAIR (ushort2 dword);
// half-waves take even/odd edges -> one gather instr covers 2 edges.

__global__ __launch_bounds__(THREADS) void agg_kernel(const unsigned* __restrict__ srt,
                                                      const int* __restrict__ row,
                                                      const float* __restrict__ dinv,
                                                      const unsigned* __restrict__ H2,  // [N][32] dwords (bf16 pairs)
                                                      const float* __restrict__ bias,
                                                      float* __restrict__ out, int N, int E) {
    const int idx = blockIdx.x * blockDim.x + threadIdx.x;
    const int node = idx >> 6;
    if (node >= N) return;
    const int l = threadIdx.x & 63;
    const int half = l >> 5;          // 0: even edges, 1: odd edges
    const int f2 = l & 31;            // feature pair (2*f2, 2*f2+1)
    const int start = row[node];
    const int end = (node + 1 < N) ? row[node + 1] : E;
    float acc0 = 0.0f, acc1 = 0.0f;

    int base = start;
    for (; base + 8 <= end; base += 8) {
        const int j = base + half;
        const unsigned sA = srt[j + 0];
        const unsigned sB = srt[j + 2];
        const unsigned sC = srt[j + 4];
        const unsigned sD = srt[j + 6];
        const unsigned vA = H2[(size_t)sA * 32 + f2];
        const unsigned vB = H2[(size_t)sB * 32 + f2];
        const unsigned vC = H2[(size_t)sC * 32 + f2];
        const unsigned vD = H2[(size_t)sD * 32 + f2];
        acc0 += bflo(vA); acc1 += bfhi(vA);
        acc0 += bflo(vB); acc1 += bfhi(vB);
        acc0 += bflo(vC); acc1 += bfhi(vC);
        acc0 += bflo(vD); acc1 += bfhi(vD);
    }
    if (base < end) {
        unsigned s[4];
        bool ok[4];
#pragma unroll
        for (int k = 0; k < 4; ++k) {
            const int jj = base + 2 * k + half;
            ok[k] = jj < end;
            s[k] = srt[ok[k] ? jj : start];
        }
        unsigned v[4];
#pragma unroll
        for (int k = 0; k < 4; ++k) v[k] = H2[(size_t)s[k] * 32 + f2];
#pragma unroll
        for (int k = 0; k < 4; ++k) {
            acc0 += ok[k] ? bflo(v[k]) : 0.0f;
            acc1 += ok[k] ? bfhi(v[k]) : 0.0f;
        }
    }

    acc0 += __shfl_xor(acc0, 32, 64);
    acc1 += __shfl_xor(acc1, 32, 64);
    if (half == 0) {
        const unsigned sv = H2[(size_t)node * 32 + f2];   // self-loop row
        const float d = dinv[node];
        const float2 b = *(const float2*)(bias + f2 * 2);
        const float o0 = fmaxf(fmaf(acc0 + bflo(sv), d, b.x), 0.0f);
        const float o1 = fmaxf(fmaf(acc1 + bfhi(sv), d, b.y), 0.0f);
        float2 o = {o0, o1};
        *(float2*)(out + (size_t)node * 64 + f2 * 2) = o;
    }
}

// ---- Launch ----------------------------------------------------------------

extern "C" void kernel_launch(void* const* d_in, const int* in_sizes, int n_in,
                              void* d_out, int out_size, void* d_ws, size_t ws_size,
                              hipStream_t stream) {
    const float* x   = (const float*)d_in[0];
    const int*   ei  = (const int*)d_in[1];   // [2, E] int32
    const float* W1  = (const float*)d_in[3];
    const float* b1  = (const float*)d_in[4];
    const float* W2  = (const float*)d_in[5];
    const float* b2  = (const float*)d_in[6];
    const float* Wfc = (const float*)d_in[7];
    const float* bfc = (const float*)d_in[8];
    float* out = (float*)d_out;

    const int N = in_sizes[0] / 128;
    const int E = in_sizes[1] / 2;
    const int* src = ei;
    const int* dst = ei + E;

    const int nb   = (N + BKT - 1) / BKT;     // 391 buckets
    const int nblk = (E + EPB - 1) / EPB;     // 391 edge-chunks

    // ws: bh[nb*nblk] | btot[nb] | bstart[nb+1] | stage[E] | row[N] | dinv[N]
    //     | bufF[N*64] fp32 | bufH[N*64] bf16   (~46 MB)
    int*      bh     = (int*)d_ws;
    int*      btot   = bh + (size_t)nb * nblk;
    int*      bstart = btot + nb;
    unsigned* stage  = (unsigned*)(bstart + nb + 1);
    int*      row    = (int*)(stage + E);
    float*    dinv   = (float*)(row + N);
    float*    bufF   = dinv + N;                             // fp32 [N,64]
    ushort_t* bufH   = (ushort_t*)(bufF + (size_t)N * 64);   // bf16 [N,64]

    const int gW = ((N * 64) + THREADS - 1) / THREADS;  // one wave per node

    // Partition -> sorted CSR (shared by both conv layers).
    histB_kernel<<<nblk, THREADS, 0, stream>>>(dst, E, nb, nblk, bh);
    scanS_kernel<<<nb, THREADS, 0, stream>>>(bh, nb, nblk, btot);
    scanT_kernel<<<1, 512, 0, stream>>>(btot, nb, E, bstart);
    binB_kernel<<<nblk, THREADS, 0, stream>>>(src, dst, E, nb, nblk, bh, bstart, stage);
    sortB_kernel<<<nb, THREADS, 0, stream>>>(stage, bstart, nb, N, row, dinv);

    // Layer 1: Hs1 = bf16((x @ W1)*dinv); relu1 = relu(dinv*(Hs1 self+gather)+b1) fp32
    mm_kernel<128, 64, 64, false, true, true><<<(N + 63) / 64, THREADS, 0, stream>>>(
        x, W1, nullptr, dinv, bufH, N);
    agg_kernel<<<gW, THREADS, 0, stream>>>(stage, row, dinv, (const unsigned*)bufH, b1, bufF, N, E);

    // Layer 2
    mm_kernel<64, 64, 64, false, true, true><<<(N + 63) / 64, THREADS, 0, stream>>>(
        bufF, W2, nullptr, dinv, bufH, N);
    agg_kernel<<<gW, THREADS, 0, stream>>>(stage, row, dinv, (const unsigned*)bufH, b2, bufF, N, E);

    // FC: out = relu2 @ Wfc + bfc (fp32 in/out)
    mm_kernel<64, 32, 128, true, false, false><<<(N + 127) / 128, THREADS, 0, stream>>>(
        bufF, Wfc, bfc, nullptr, out, N);
}

// Round 10
// 294.051 us; speedup vs baseline: 1.0534x; 1.0227x over previous
//
#include <hip/hip_runtime.h>

// GCN: 2x (GCNConv + ReLU) + FC.  N=100000, E=1600000, F: 128 -> 64 -> 64 -> 32. fp32.
//
// R10: MLP fixes from R9 rocprof (mm latency-bound on X stream, VALU 27%;
// agg vmem-instruction-bound).
// - mm: depth-2 prefetch (8 float4 in flight/thread), W-only LDS as R9.
// - agg: 16-edge chunks; srt indices read via wave-uniform (readfirstlane)
//   pointer -> scalar/broadcast loads; halves take edges 0-7 / 8-15; 8 gathers
//   in flight. Tail reads the same way (past-end reads stay inside ws), with
//   clamped indices + masked accumulate.
// Hs tables bf16 (R7), partition passes (R6) unchanged.

#define THREADS 256
#define EPB 4096          // edges per block in hist/bin passes
#define BKT 256           // nodes per bucket (dlocal = dst & 255)
#define SORT_CAP 8192     // max edges per bucket in LDS (mean 4092, sigma ~64)

typedef unsigned short ushort_t;

__device__ __forceinline__ ushort_t f2bf(float f) {  // round-to-nearest-even
    unsigned u = __float_as_uint(f);
    u += 0x7FFFu + ((u >> 16) & 1u);
    return (ushort_t)(u >> 16);
}
__device__ __forceinline__ float bflo(unsigned v) { return __uint_as_float(v << 16); }
__device__ __forceinline__ float bfhi(unsigned v) { return __uint_as_float(v & 0xFFFF0000u); }

// ---- Pass 1: per-(block,bucket) histogram ---------------------------------

__global__ __launch_bounds__(THREADS) void histB_kernel(const int* __restrict__ dst, int E,
                                                        int nb, int nblk,
                                                        int* __restrict__ bh) {
    __shared__ int h[512];
    for (int i = threadIdx.x; i < nb; i += THREADS) h[i] = 0;
    __syncthreads();
    const int e0 = blockIdx.x * EPB;
    const int e1 = min(e0 + EPB, E);
    for (int e = e0 + threadIdx.x; e < e1; e += THREADS)
        atomicAdd(&h[dst[e] >> 8], 1);
    __syncthreads();
    for (int i = threadIdx.x; i < nb; i += THREADS)
        bh[(size_t)i * nblk + blockIdx.x] = h[i];   // [bucket][block]
}

// ---- Pass 2a: per-bucket row scan (block b owns row b) --------------------

__global__ __launch_bounds__(THREADS) void scanS_kernel(int* __restrict__ bh,
                                                        int nb, int nblk,
                                                        int* __restrict__ btot) {
    __shared__ int s[THREADS];
    const int b = blockIdx.x, t = threadIdx.x;
    int* rowp = bh + (size_t)b * nblk;
    const int run = (nblk + THREADS - 1) / THREADS;
    const int lo = min(t * run, nblk), hi = min(lo + run, nblk);
    int v[4];
    int sum = 0;
    for (int i = lo; i < hi; ++i) { v[i - lo] = rowp[i]; sum += v[i - lo]; }
    s[t] = sum;
    __syncthreads();
    for (int off = 1; off < THREADS; off <<= 1) {
        int u = (t >= off) ? s[t - off] : 0;
        __syncthreads();
        s[t] += u;
        __syncthreads();
    }
    int pre = s[t] - sum;
    for (int i = lo; i < hi; ++i) { rowp[i] = pre; pre += v[i - lo]; }
    if (t == THREADS - 1) btot[b] = s[t];
}

// ---- Pass 2b: scan bucket totals -> bstart[0..nb], bstart[nb]=E -----------

__global__ __launch_bounds__(512) void scanT_kernel(const int* __restrict__ btot,
                                                    int nb, int E,
                                                    int* __restrict__ bstart) {
    __shared__ int s[512];
    const int t = threadIdx.x;
    const int v = (t < nb) ? btot[t] : 0;
    s[t] = v;
    __syncthreads();
    for (int off = 1; off < 512; off <<= 1) {
        int u = (t >= off) ? s[t - off] : 0;
        __syncthreads();
        s[t] += u;
        __syncthreads();
    }
    if (t < nb) bstart[t] = s[t] - v;
    if (t == 0) bstart[nb] = E;
}

// ---- Pass 3: scatter edges into bucket-contiguous staging -----------------

__global__ __launch_bounds__(THREADS) void binB_kernel(const int* __restrict__ src,
                                                       const int* __restrict__ dst, int E,
                                                       int nb, int nblk,
                                                       const int* __restrict__ bh,
                                                       const int* __restrict__ bstart,
                                                       unsigned* __restrict__ stage) {
    __shared__ int cur[512];
    for (int i = threadIdx.x; i < nb; i += THREADS)
        cur[i] = bstart[i] + bh[(size_t)i * nblk + blockIdx.x];
    __syncthreads();
    const int e0 = blockIdx.x * EPB;
    const int e1 = min(e0 + EPB, E);
    for (int e = e0 + threadIdx.x; e < e1; e += THREADS) {
        const int d = dst[e];
        const int pos = atomicAdd(&cur[d >> 8], 1);
        stage[pos] = ((unsigned)(d & (BKT - 1)) << 17) | (unsigned)src[e];
    }
}

// ---- Pass 4: per-bucket in-LDS counting sort (in place) + row/dinv --------

__global__ __launch_bounds__(THREADS) void sortB_kernel(unsigned* __restrict__ stage,
                                                        const int* __restrict__ bstart,
                                                        int nb, int N,
                                                        int* __restrict__ row,
                                                        float* __restrict__ dinv) {
    __shared__ unsigned buf[SORT_CAP];
    __shared__ int cnt[BKT], cur[BKT], scn[BKT];
    const int b = blockIdx.x, t = threadIdx.x;
    const int bs = bstart[b];
    const int be = bstart[b + 1];
    const int m = be - bs;
    cnt[t] = 0;
    __syncthreads();
    for (int i = t; i < m; i += THREADS) {
        const unsigned v = stage[bs + i];
        buf[i] = v;
        atomicAdd(&cnt[v >> 17], 1);
    }
    __syncthreads();
    const int c = cnt[t];
    scn[t] = c;
    __syncthreads();
    for (int off = 1; off < BKT; off <<= 1) {
        int u = (t >= off) ? scn[t - off] : 0;
        __syncthreads();
        scn[t] += u;
        __syncthreads();
    }
    const int excl = scn[t] - c;
    cur[t] = excl;
    const int node = b * BKT + t;
    if (node < N) {
        row[node] = bs + excl;
        dinv[node] = rsqrtf((float)c + 1.0f);  // +1 self-loop
    }
    __syncthreads();
    for (int i = t; i < m; i += THREADS) {
        const unsigned v = buf[i];
        const int pos = atomicAdd(&cur[v >> 17], 1);
        stage[bs + pos] = v & 0x1FFFFu;        // strip dlocal: plain src
    }
}

// ---- Dense matmul: Y[N,M] = (X[N,K] @ W[K,M]) [*dinv[row]] [+bias] ---------
// W-only LDS; X streamed global->reg with DEPTH-2 prefetch (8 float4 in
// flight per thread). OOB rows: pointer clamped; store guard discards.

template <int K, int M, int TILE_R, bool BIAS, bool SCALE, bool OUT_BF16, typename OutT>
__global__ __launch_bounds__(THREADS) void mm_kernel(const float* __restrict__ X,
                                                     const float* __restrict__ W,
                                                     const float* __restrict__ bias,
                                                     const float* __restrict__ dinv,
                                                     OutT* __restrict__ Y, int N) {
    static_assert((TILE_R / 4) * (M / 4) == THREADS, "tile/thread mismatch");
    __shared__ float Ws[K * M];
    const int t = threadIdx.x;
    const int row0 = blockIdx.x * TILE_R;

    for (int i = t; i < K * M / 4; i += THREADS)
        ((float4*)Ws)[i] = ((const float4*)W)[i];
    __syncthreads();

    constexpr int CG = M / 4;
    const int rg = t / CG;
    const int cg = t % CG;
    const int r0 = row0 + rg * 4;
    const float* xp0 = X + (size_t)min(r0 + 0, N - 1) * K;
    const float* xp1 = X + (size_t)min(r0 + 1, N - 1) * K;
    const float* xp2 = X + (size_t)min(r0 + 2, N - 1) * K;
    const float* xp3 = X + (size_t)min(r0 + 3, N - 1) * K;
    const float* wb = &Ws[cg * 4];
    float acc[4][4] = {};

#define GCN_STEP(XV, WV)                                                                  \
    acc[0][0] = fmaf(xv0.XV, WV.x, acc[0][0]); acc[0][1] = fmaf(xv0.XV, WV.y, acc[0][1]); \
    acc[0][2] = fmaf(xv0.XV, WV.z, acc[0][2]); acc[0][3] = fmaf(xv0.XV, WV.w, acc[0][3]); \
    acc[1][0] = fmaf(xv1.XV, WV.x, acc[1][0]); acc[1][1] = fmaf(xv1.XV, WV.y, acc[1][1]); \
    acc[1][2] = fmaf(xv1.XV, WV.z, acc[1][2]); acc[1][3] = fmaf(xv1.XV, WV.w, acc[1][3]); \
    acc[2][0] = fmaf(xv2.XV, WV.x, acc[2][0]); acc[2][1] = fmaf(xv2.XV, WV.y, acc[2][1]); \
    acc[2][2] = fmaf(xv2.XV, WV.z, acc[2][2]); acc[2][3] = fmaf(xv2.XV, WV.w, acc[2][3]); \
    acc[3][0] = fmaf(xv3.XV, WV.x, acc[3][0]); acc[3][1] = fmaf(xv3.XV, WV.y, acc[3][1]); \
    acc[3][2] = fmaf(xv3.XV, WV.z, acc[3][2]); acc[3][3] = fmaf(xv3.XV, WV.w, acc[3][3]);

#define GCN_CHUNK(KK)                                                   \
    {                                                                   \
        const float4 wv0 = *(const float4*)(wb + (size_t)(KK + 0) * M); \
        const float4 wv1 = *(const float4*)(wb + (size_t)(KK + 1) * M); \
        const float4 wv2 = *(const float4*)(wb + (size_t)(KK + 2) * M); \
        const float4 wv3 = *(const float4*)(wb + (size_t)(KK + 3) * M); \
        GCN_STEP(x, wv0)                                                \
        GCN_STEP(y, wv1)                                                \
        GCN_STEP(z, wv2)                                                \
        GCN_STEP(w, wv3)                                                \
    }

    // Depth-2 pipeline: A = chunk k, B = chunk k+4; load k+8 each iteration.
    float4 A0 = *(const float4*)(xp0 + 0), A1 = *(const float4*)(xp1 + 0);
    float4 A2 = *(const float4*)(xp2 + 0), A3 = *(const float4*)(xp3 + 0);
    float4 B0 = *(const float4*)(xp0 + 4), B1 = *(const float4*)(xp1 + 4);
    float4 B2 = *(const float4*)(xp2 + 4), B3 = *(const float4*)(xp3 + 4);
#pragma unroll 4
    for (int k = 0; k < K; k += 4) {
        const float4 xv0 = A0, xv1 = A1, xv2 = A2, xv3 = A3;
        A0 = B0; A1 = B1; A2 = B2; A3 = B3;
        const int kn = min(k + 8, K - 4);
        B0 = *(const float4*)(xp0 + kn);
        B1 = *(const float4*)(xp1 + kn);
        B2 = *(const float4*)(xp2 + kn);
        B3 = *(const float4*)(xp3 + kn);
        GCN_CHUNK(k)
    }
#undef GCN_CHUNK
#undef GCN_STEP

#pragma unroll
    for (int i = 0; i < 4; ++i) {
        const int r = r0 + i;
        if (r < N) {
            float4 o = {acc[i][0], acc[i][1], acc[i][2], acc[i][3]};
            if (SCALE) {
                const float d = dinv[r];
                o.x *= d; o.y *= d; o.z *= d; o.w *= d;
            }
            if (BIAS) {
                o.x += bias[cg * 4 + 0]; o.y += bias[cg * 4 + 1];
                o.z += bias[cg * 4 + 2]; o.w += bias[cg * 4 + 3];
            }
            if (OUT_BF16) {
                ushort4 p = {f2bf(o.x), f2bf(o.y), f2bf(o.z), f2bf(o.w)};
                *(ushort4*)((ushort_t*)Y + (size_t)r * M + cg * 4) = p;
            } else {
                *(float4*)((float*)Y + (size_t)r * M + cg * 4) = o;
            }
        }
    }
}

// ---- Aggregation: wave per node; lane owns a feature PAIR (ushort2 dword).
// 16-edge chunks: srt read through a wave-uniform pointer (scalar/broadcast
// loads); half 0 takes edges 0-7, half 1 takes 8-15; 8 gathers in flight.
// Tail: same read (past-end stays inside ws), clamped indices, masked adds.

__global__ __launch_bounds__(THREADS) void agg_kernel(const unsigned* __restrict__ srt,
                                                      const int* __restrict__ row,
                                                      const float* __restrict__ dinv,
                                                      const unsigned* __restrict__ H2,  // [N][32] dwords (bf16 pairs)
                                                      const float* __restrict__ bias,
                                                      float* __restrict__ out, int N, int E) {
    const int idx = blockIdx.x * blockDim.x + threadIdx.x;
    const int node = idx >> 6;
    if (node >= N) return;
    const int l = threadIdx.x & 63;
    const int half = l >> 5;          // 0: edges 0-7 of chunk, 1: edges 8-15
    const int f2 = l & 31;            // feature pair (2*f2, 2*f2+1)
    const int start = row[node];
    const int end = (node + 1 < N) ? row[node + 1] : E;
    float acc0 = 0.0f, acc1 = 0.0f;

    int base = start;
    for (; base + 16 <= end; base += 16) {
        const unsigned* sp = srt + __builtin_amdgcn_readfirstlane(base);
        const unsigned g0 = sp[0],  g1 = sp[1],  g2 = sp[2],  g3 = sp[3];
        const unsigned g4 = sp[4],  g5 = sp[5],  g6 = sp[6],  g7 = sp[7];
        const unsigned h0 = sp[8],  h1 = sp[9],  h2 = sp[10], h3 = sp[11];
        const unsigned h4 = sp[12], h5 = sp[13], h6 = sp[14], h7 = sp[15];
        const unsigned e0 = half ? h0 : g0, e1 = half ? h1 : g1;
        const unsigned e2 = half ? h2 : g2, e3 = half ? h3 : g3;
        const unsigned e4 = half ? h4 : g4, e5 = half ? h5 : g5;
        const unsigned e6 = half ? h6 : g6, e7 = half ? h7 : g7;
        const unsigned v0 = H2[(size_t)e0 * 32 + f2];
        const unsigned v1 = H2[(size_t)e1 * 32 + f2];
        const unsigned v2 = H2[(size_t)e2 * 32 + f2];
        const unsigned v3 = H2[(size_t)e3 * 32 + f2];
        const unsigned v4 = H2[(size_t)e4 * 32 + f2];
        const unsigned v5 = H2[(size_t)e5 * 32 + f2];
        const unsigned v6 = H2[(size_t)e6 * 32 + f2];
        const unsigned v7 = H2[(size_t)e7 * 32 + f2];
        acc0 += bflo(v0); acc1 += bfhi(v0);
        acc0 += bflo(v1); acc1 += bfhi(v1);
        acc0 += bflo(v2); acc1 += bfhi(v2);
        acc0 += bflo(v3); acc1 += bfhi(v3);
        acc0 += bflo(v4); acc1 += bfhi(v4);
        acc0 += bflo(v5); acc1 += bfhi(v5);
        acc0 += bflo(v6); acc1 += bfhi(v6);
        acc0 += bflo(v7); acc1 += bfhi(v7);
    }
    if (base < end) {
        const unsigned* sp = srt + __builtin_amdgcn_readfirstlane(base);
        const unsigned cap = (unsigned)(N - 1);
        const int j0 = base + half * 8;
#pragma unroll
        for (int k = 0; k < 8; ++k) {
            const unsigned raw = half ? sp[8 + k] : sp[k];   // may be past end: in-ws garbage
            const bool ok = (j0 + k) < end;
            const unsigned s = min(raw & 0x1FFFFu, cap);     // clamp to valid H2 row
            const unsigned v = H2[(size_t)s * 32 + f2];
            acc0 += ok ? bflo(v) : 0.0f;
            acc1 += ok ? bfhi(v) : 0.0f;
        }
    }

    acc0 += __shfl_xor(acc0, 32, 64);
    acc1 += __shfl_xor(acc1, 32, 64);
    if (half == 0) {
        const unsigned sv = H2[(size_t)node * 32 + f2];   // self-loop row
        const float d = dinv[node];
        const float2 b = *(const float2*)(bias + f2 * 2);
        const float o0 = fmaxf(fmaf(acc0 + bflo(sv), d, b.x), 0.0f);
        const float o1 = fmaxf(fmaf(acc1 + bfhi(sv), d, b.y), 0.0f);
        float2 o = {o0, o1};
        *(float2*)(out + (size_t)node * 64 + f2 * 2) = o;
    }
}

// ---- Launch ----------------------------------------------------------------

extern "C" void kernel_launch(void* const* d_in, const int* in_sizes, int n_in,
                              void* d_out, int out_size, void* d_ws, size_t ws_size,
                              hipStream_t stream) {
    const float* x   = (const float*)d_in[0];
    const int*   ei  = (const int*)d_in[1];   // [2, E] int32
    const float* W1  = (const float*)d_in[3];
    const float* b1  = (const float*)d_in[4];
    const float* W2  = (const float*)d_in[5];
    const float* b2  = (const float*)d_in[6];
    const float* Wfc = (const float*)d_in[7];
    const float* bfc = (const float*)d_in[8];
    float* out = (float*)d_out;

    const int N = in_sizes[0] / 128;
    const int E = in_sizes[1] / 2;
    const int* src = ei;
    const int* dst = ei + E;

    const int nb   = (N + BKT - 1) / BKT;     // 391 buckets
    const int nblk = (E + EPB - 1) / EPB;     // 391 edge-chunks

    // ws: bh[nb*nblk] | btot[nb] | bstart[nb+1] | stage[E] | row[N] | dinv[N]
    //     | bufF[N*64] fp32 | bufH[N*64] bf16   (~46 MB)
    int*      bh     = (int*)d_ws;
    int*      btot   = bh + (size_t)nb * nblk;
    int*      bstart = btot + nb;
    unsigned* stage  = (unsigned*)(bstart + nb + 1);
    int*      row    = (int*)(stage + E);
    float*    dinv   = (float*)(row + N);
    float*    bufF   = dinv + N;                             // fp32 [N,64]
    ushort_t* bufH   = (ushort_t*)(bufF + (size_t)N * 64);   // bf16 [N,64]

    const int gW = ((N * 64) + THREADS - 1) / THREADS;  // one wave per node

    // Partition -> sorted CSR (shared by both conv layers).
    histB_kernel<<<nblk, THREADS, 0, stream>>>(dst, E, nb, nblk, bh);
    scanS_kernel<<<nb, THREADS, 0, stream>>>(bh, nb, nblk, btot);
    scanT_kernel<<<1, 512, 0, stream>>>(btot, nb, E, bstart);
    binB_kernel<<<nblk, THREADS, 0, stream>>>(src, dst, E, nb, nblk, bh, bstart, stage);
    sortB_kernel<<<nb, THREADS, 0, stream>>>(stage, bstart, nb, N, row, dinv);

    // Layer 1: Hs1 = bf16((x @ W1)*dinv); relu1 = relu(dinv*(Hs1 self+gather)+b1) fp32
    mm_kernel<128, 64, 64, false, true, true><<<(N + 63) / 64, THREADS, 0, stream>>>(
        x, W1, nullptr, dinv, bufH, N);
    agg_kernel<<<gW, THREADS, 0, stream>>>(stage, row, dinv, (const unsigned*)bufH, b1, bufF, N, E);

    // Layer 2
    mm_kernel<64, 64, 64, false, true, true><<<(N + 63) / 64, THREADS, 0, stream>>>(
        bufF, W2, nullptr, dinv, bufH, N);
    agg_kernel<<<gW, THREADS, 0, stream>>>(stage, row, dinv, (const unsigned*)bufH, b2, bufF, N, E);

    // FC: out = relu2 @ Wfc + bfc (fp32 in/out)
    mm_kernel<64, 32, 128, true, false, false><<<(N + 127) / 128, THREADS, 0, stream>>>(
        bufF, Wfc, bfc, nullptr, out, N);
}